// Round 13
// baseline (339.825 us; speedup 1.0000x reference)
//
#include <hip/hip_runtime.h>
#include <hip/hip_bf16.h>
#include <cstdint>
#include <cstddef>

#define S 4096
#define D 1024
#define H 16
#define HD 64
#define BATCH 2
#define M_TOK 8192   // BATCH*S
#define K2 2048

typedef short short8 __attribute__((ext_vector_type(8)));
typedef __bf16 bf16x8 __attribute__((ext_vector_type(8)));
typedef float f32x4 __attribute__((ext_vector_type(4)));
typedef unsigned int u32;

static __device__ __forceinline__ ushort f2bf(float f) {
  union { float f; uint32_t u; } v; v.f = f;
  uint32_t u = v.u + 0x7FFFu + ((v.u >> 16) & 1u);
  return (ushort)(u >> 16);
}
static __device__ __forceinline__ float bf2f(ushort h) {
  union { uint32_t u; float f; } v; v.u = ((uint32_t)h) << 16; return v.f;
}
static __device__ __forceinline__ uint32_t cvtpk(float lo, float hi) {
  uint32_t r;
  asm("v_cvt_pk_bf16_f32 %0, %1, %2" : "=v"(r) : "v"(lo), "v"(hi));
  return r;
}
static __device__ __forceinline__ float vexp2(float x) {
  float r;
  asm("v_exp_f32 %0, %1" : "=v"(r) : "v"(x));
  return r;
}
static __device__ __forceinline__ bf16x8 pack4(uint32_t a, uint32_t b, uint32_t c, uint32_t d) {
  union { uint32_t u[4]; bf16x8 v; } z;
  z.u[0] = a; z.u[1] = b; z.u[2] = c; z.u[3] = d;
  return z.v;
}
// async global->LDS, 16B per lane; LDS dest = wave-uniform base + lane*16
static __device__ __forceinline__ void gld16(const void* g, void* l) {
  __builtin_amdgcn_global_load_lds(
      (const __attribute__((address_space(1))) u32*)g,
      (__attribute__((address_space(3))) u32*)l, 16, 0, 0);
}
static __device__ __forceinline__ ushort sgn(float a) {
  return a > 0.f ? 0x3F80 : (a < 0.f ? 0xBF80 : 0);
}

// ---------------- prep: x -> [hi|lo] bf16 concat (vectorized) ----------------
__global__ void prep_x(const float* __restrict__ x, ushort* __restrict__ xcat) {
  int i = blockIdx.x * blockDim.x + threadIdx.x;
  const int total = M_TOK * 128;   // groups of 8 floats
  for (; i < total; i += gridDim.x * blockDim.x) {
    int row = i >> 7, c8 = (i & 127) * 8;
    const float* px = &x[(size_t)row * 1024 + c8];
    float4 a = *(const float4*)px;
    float4 b = *(const float4*)(px + 4);
    float va[8] = {a.x, a.y, a.z, a.w, b.x, b.y, b.z, b.w};
    union { ushort u[8]; short8 v; } Hh, Ll;
#pragma unroll
    for (int j = 0; j < 8; ++j) {
      ushort h = f2bf(va[j]);
      Hh.u[j] = h;
      Ll.u[j] = f2bf(va[j] - bf2f(h));
    }
    *(short8*)&xcat[(size_t)row * K2 + c8] = Hh.v;
    *(short8*)&xcat[(size_t)row * K2 + 1024 + c8] = Ll.v;
  }
}

// W -> sign(W) bf16; Wq/Wk/Wv concat rows [3072][1024]; Wo separate
__global__ void prep_w(const float* __restrict__ wq, const float* __restrict__ wk,
                       const float* __restrict__ wv, const float* __restrict__ wo,
                       ushort* __restrict__ wcat, ushort* __restrict__ wob) {
  int i = blockIdx.x * blockDim.x + threadIdx.x;
  const int total = (D * D) / 4;
  for (; i < total; i += gridDim.x * blockDim.x) {
    float4 a;
    union { ushort u[4]; uint2 v; } t;
    a = *(const float4*)&wq[i * 4];
    t.u[0] = sgn(a.x); t.u[1] = sgn(a.y); t.u[2] = sgn(a.z); t.u[3] = sgn(a.w);
    *(uint2*)&wcat[i * 4] = t.v;
    a = *(const float4*)&wk[i * 4];
    t.u[0] = sgn(a.x); t.u[1] = sgn(a.y); t.u[2] = sgn(a.z); t.u[3] = sgn(a.w);
    *(uint2*)&wcat[D * D + i * 4] = t.v;
    a = *(const float4*)&wv[i * 4];
    t.u[0] = sgn(a.x); t.u[1] = sgn(a.y); t.u[2] = sgn(a.z); t.u[3] = sgn(a.w);
    *(uint2*)&wcat[2 * D * D + i * 4] = t.v;
    a = *(const float4*)&wo[i * 4];
    t.u[0] = sgn(a.x); t.u[1] = sgn(a.y); t.u[2] = sgn(a.z); t.u[3] = sgn(a.w);
    *(uint2*)&wob[i * 4] = t.v;
  }
}

// ---------------- GEMM (m97 structure): C = A (M x KK @ stride AST) * B^T; B rows wrap at BROW ----------------
// EPI 0: Q/K hi-lo epilogue (proj = bn>>3). EPI 1: V^T permuted epilogue. EPI 2: fp32 + bias.
template<int EPI, int KK, int BROW, int AST>
__global__ __launch_bounds__(256) void gemm97(
    const ushort* __restrict__ A, const ushort* __restrict__ Bw,
    ushort* __restrict__ q_hi, ushort* __restrict__ q_lo,
    ushort* __restrict__ k_hi, ushort* __restrict__ k_lo,
    ushort* __restrict__ v_t,
    float* __restrict__ of, const float* __restrict__ bias)
{
  __shared__ ushort smA[128 * 32];
  __shared__ ushort smB[128 * 32];
  const int tid = threadIdx.x;
  const int l = tid & 63;
  const int w = tid >> 6;
  const int x = l & 15, g = l >> 4;
  const int wm = w >> 1, wn = w & 1;
  const int bm = blockIdx.x, bn = blockIdx.y;

  const ushort* gA[2]; const ushort* gB[2]; int ldso[2];
#pragma unroll
  for (int p = 0; p < 2; ++p) {
    int q = p * 256 + tid;                    // chunk id: row=q>>2, 16B-blk=q&3
    gA[p] = &A[(size_t)(bm * 128 + (q >> 2)) * AST + (q & 3) * 8];
    gB[p] = &Bw[(size_t)(bn * 128 + (q >> 2)) * BROW + (q & 3) * 8];
    ldso[p] = (p * 256 + w * 64) * 8;         // wave-uniform LDS chunk base
  }

  f32x4 acc[4][4] = {};

  for (int k0 = 0; k0 < KK; k0 += 32) {
    __syncthreads();
#pragma unroll
    for (int p = 0; p < 2; ++p) {
      gld16(gA[p] + k0, &smA[ldso[p]]);
      gld16(gB[p] + (k0 & (BROW - 1)), &smB[ldso[p]]);
    }
    __syncthreads();
    bf16x8 af[4], bf_[4];
#pragma unroll
    for (int m = 0; m < 4; ++m)
      af[m] = *(const bf16x8*)&smA[(wm * 64 + m * 16 + x) * 32 + g * 8];
#pragma unroll
    for (int n = 0; n < 4; ++n)
      bf_[n] = *(const bf16x8*)&smB[(wn * 64 + n * 16 + x) * 32 + g * 8];
#pragma unroll
    for (int m = 0; m < 4; ++m)
#pragma unroll
      for (int n = 0; n < 4; ++n)
        acc[m][n] = __builtin_amdgcn_mfma_f32_16x16x32_bf16(af[m], bf_[n], acc[m][n], 0, 0, 0);
  }

#pragma unroll
  for (int m = 0; m < 4; ++m)
#pragma unroll
    for (int n = 0; n < 4; ++n)
#pragma unroll
      for (int r = 0; r < 4; ++r) {
        int rowg = bm * 128 + wm * 64 + m * 16 + g * 4 + r;
        int colg = bn * 128 + wn * 64 + n * 16 + x;
        float v = acc[m][n][r];
        if (EPI == 2) {
          of[(size_t)rowg * D + colg] = v + bias[colg];
        } else {
          int bi = rowg >> 12, ntok = rowg & 4095;
          int cg = colg & 1023;
          int h = cg >> 6, hd = cg & 63;
          size_t bhb = (size_t)(bi * H + h) * (S * HD);
          if (EPI == 0) {
            const int proj = bn >> 3;          // 0=q 1=k (uniform per block)
            ushort* oh = (proj == 0) ? q_hi : k_hi;
            ushort* ol = (proj == 0) ? q_lo : k_lo;
            size_t off = bhb + (size_t)ntok * HD + hd;
            ushort hiv = f2bf(v);
            oh[off] = hiv;
            ol[off] = f2bf(v - bf2f(hiv));
          } else {
            // V^T with within-32-token permutation matching MFMA k-slots:
            // token t=16b+4g+r  ->  pos 8g+4b+r
            int t5 = ntok & 31;
            int pos = ((t5 >> 2) & 3) * 8 + ((t5 >> 4) & 1) * 4 + (t5 & 3);
            v_t[bhb + (size_t)hd * S + (ntok & ~31) + pos] = f2bf(v);
          }
        }
      }
}

// ---------------- flash v13: PERSISTENT blocks + dynamic heavy-first work queue ----------------
// 768 blocks (3/CU by 48KB LDS, 12 waves/CU sustained). Items n in [0,1024):
// bh = n & 31, qt = 31 - (n>>5)  (heavy tiles dispatched first). Body = flash5 (best).
__global__ __launch_bounds__(256) void flash13(
    const ushort* __restrict__ qhi, const ushort* __restrict__ qlo,
    const ushort* __restrict__ khi, const ushort* __restrict__ klo,
    const ushort* __restrict__ vt, ushort* __restrict__ ctx,
    u32* __restrict__ ctr)
{
  __shared__ ushort smKhi[2][64 * 64];
  __shared__ ushort smKlo[2][64 * 64];
  __shared__ ushort smVT[2][64 * 64];
  __shared__ int item_s;

  const int tid = threadIdx.x;
  const int l = tid & 63;
  const int w = tid >> 6;
  const int x = l & 15;
  const int g = l >> 4;

  // item-invariant staging constants (source pre-swizzled: LDS chunk pb holds logical blk pb^(rr&7))
  int soff_k[2]; size_t soff_v[2]; int ldso[2];
#pragma unroll
  for (int p = 0; p < 2; ++p) {
    int q = p * 256 + tid;
    int r2 = q >> 3;
    int sb = (q & 7) ^ (r2 & 7);
    soff_k[p] = r2 * HD + sb * 8;
    soff_v[p] = (size_t)r2 * S + sb * 8;
    ldso[p] = (p * 256 + w * 64) * 8;
  }
  const float C1 = 0.125f * 1.44269504f;   // 1/sqrt(64) folded into exp2
  const float TH = 8.0f / C1;              // defer-max threshold (raw score units)

  for (;;) {
    if (tid == 0) item_s = (int)atomicAdd(ctr, 1u);
    __syncthreads();
    const int item = item_s;
    __syncthreads();
    if (item >= 32 * 32) break;

    const int bh = item & 31;
    const int qt = 31 - (item >> 5);
    const int qbase = qt * 128;
    const size_t qkbase = (size_t)bh * S * HD;
    const ushort* khb = khi + qkbase;
    const ushort* klb = klo + qkbase;
    const ushort* vtb = vt + qkbase;

    // Q fragments (B-operand): [qset][hi/lo][c]
    bf16x8 bq[2][2][2];
#pragma unroll
    for (int qs = 0; qs < 2; ++qs) {
      int qrow = qbase + w * 32 + qs * 16 + x;
      size_t base = qkbase + (size_t)qrow * HD + g * 8;
      bq[qs][0][0] = *(const bf16x8*)&qhi[base];
      bq[qs][0][1] = *(const bf16x8*)&qhi[base + 32];
      bq[qs][1][0] = *(const bf16x8*)&qlo[base];
      bq[qs][1][1] = *(const bf16x8*)&qlo[base + 32];
    }

    float mrun[2] = {-1e30f, -1e30f};
    float lrun[2] = {0.f, 0.f};   // lane-partial; reduced at epilogue
    f32x4 oacc[2][4] = {};

    const int kvmax = (qbase + 127) >> 6;
    const int qmaxw = qbase + w * 32 + 31;

    // prologue: stage tile 0 into buf 0
#pragma unroll
    for (int p = 0; p < 2; ++p) {
      gld16(khb + soff_k[p], &smKhi[0][ldso[p]]);
      gld16(klb + soff_k[p], &smKlo[0][ldso[p]]);
      gld16(vtb + soff_v[p], &smVT[0][ldso[p]]);
    }
    __syncthreads();

    int cur = 0;
    for (int kv = 0; kv <= kvmax; ++kv) {
      if (kv < kvmax) {
        const ushort* kh = khb + (size_t)(kv + 1) * (64 * HD);
        const ushort* kl = klb + (size_t)(kv + 1) * (64 * HD);
        const ushort* vp = vtb + (size_t)(kv + 1) * 64;
        int nb = cur ^ 1;
#pragma unroll
        for (int p = 0; p < 2; ++p) {
          gld16(kh + soff_k[p], &smKhi[nb][ldso[p]]);
          gld16(kl + soff_k[p], &smKlo[nb][ldso[p]]);
          gld16(vp + soff_v[p], &smVT[nb][ldso[p]]);
        }
      }

      if (kv * 64 <= qmaxw) {
        const ushort* bKhi = smKhi[cur];
        const ushort* bKlo = smKlo[cur];
        const ushort* bVT = smVT[cur];

        // ---- QK^T (swapped): lane holds S[k=t*16+4g+r][q=x], 3-term hi/lo ----
        f32x4 scq[2][4];
        __builtin_amdgcn_s_setprio(1);
#pragma unroll
        for (int t = 0; t < 4; ++t) {
          f32x4 a0 = {}, a1 = {};
#pragma unroll
          for (int c = 0; c < 2; ++c) {
            int pb = (t * 16 + x) * 64 + ((4 * c + g) ^ (x & 7)) * 8;
            bf16x8 kH = *(const bf16x8*)&bKhi[pb];
            bf16x8 kL = *(const bf16x8*)&bKlo[pb];
            a0 = __builtin_amdgcn_mfma_f32_16x16x32_bf16(kH, bq[0][0][c], a0, 0, 0, 0);
            a0 = __builtin_amdgcn_mfma_f32_16x16x32_bf16(kL, bq[0][0][c], a0, 0, 0, 0);
            a0 = __builtin_amdgcn_mfma_f32_16x16x32_bf16(kH, bq[0][1][c], a0, 0, 0, 0);
            a1 = __builtin_amdgcn_mfma_f32_16x16x32_bf16(kH, bq[1][0][c], a1, 0, 0, 0);
            a1 = __builtin_amdgcn_mfma_f32_16x16x32_bf16(kL, bq[1][0][c], a1, 0, 0, 0);
            a1 = __builtin_amdgcn_mfma_f32_16x16x32_bf16(kH, bq[1][1][c], a1, 0, 0, 0);
          }
          scq[0][t] = a0; scq[1][t] = a1;
        }
        __builtin_amdgcn_s_setprio(0);

        const bool needmask = (kv * 64 + 63 > qbase + w * 32);
        uint32_t pbq[2][2][4];

#pragma unroll
        for (int qs = 0; qs < 2; ++qs) {
          if (needmask) {
            int qglob = qbase + w * 32 + qs * 16 + x;
            int kb = kv * 64 + 4 * g;
#pragma unroll
            for (int t = 0; t < 4; ++t)
#pragma unroll
              for (int r = 0; r < 4; ++r)
                if (kb + t * 16 + r > qglob) scq[qs][t][r] = -1e30f;
          }
          // lane-local max tree (no shuffles on the common path)
          float mt[4];
#pragma unroll
          for (int t = 0; t < 4; ++t)
            mt[t] = fmaxf(fmaxf(scq[qs][t][0], scq[qs][t][1]),
                          fmaxf(scq[qs][t][2], scq[qs][t][3]));
          float mloc = fmaxf(fmaxf(mt[0], mt[1]), fmaxf(mt[2], mt[3]));
          // ballot-guarded defer-max
          if (__any(mloc > mrun[qs] + TH)) {
            mloc = fmaxf(mloc, __shfl_xor(mloc, 16));
            mloc = fmaxf(mloc, __shfl_xor(mloc, 32));
            float mnew = fmaxf(mrun[qs], mloc);
            float scal = vexp2((mrun[qs] - mnew) * C1);
            mrun[qs] = mnew;
            lrun[qs] *= scal;
#pragma unroll
            for (int dt = 0; dt < 4; ++dt) oacc[qs][dt] *= scal;
          }
          float mc = mrun[qs] * C1;
#pragma unroll
          for (int t = 0; t < 4; ++t)
#pragma unroll
            for (int r = 0; r < 4; ++r)
              scq[qs][t][r] = vexp2(scq[qs][t][r] * C1 - mc);
          // lane-partial sum (balanced tree)
          float st[4];
#pragma unroll
          for (int t = 0; t < 4; ++t)
            st[t] = (scq[qs][t][0] + scq[qs][t][1]) + (scq[qs][t][2] + scq[qs][t][3]);
          lrun[qs] += (st[0] + st[1]) + (st[2] + st[3]);
#pragma unroll
          for (int c = 0; c < 2; ++c) {
            pbq[qs][c][0] = cvtpk(scq[qs][2 * c][0], scq[qs][2 * c][1]);
            pbq[qs][c][1] = cvtpk(scq[qs][2 * c][2], scq[qs][2 * c][3]);
            pbq[qs][c][2] = cvtpk(scq[qs][2 * c + 1][0], scq[qs][2 * c + 1][1]);
            pbq[qs][c][3] = cvtpk(scq[qs][2 * c + 1][2], scq[qs][2 * c + 1][3]);
          }
        }

        // ---- PV: O^T += V^T * P ; V pre-permuted so A-frag is one b128 ----
        __builtin_amdgcn_s_setprio(1);
#pragma unroll
        for (int c = 0; c < 2; ++c)
#pragma unroll
          for (int dt = 0; dt < 4; ++dt) {
            bf16x8 vf = *(const bf16x8*)&bVT[(dt * 16 + x) * 64 + ((4 * c + g) ^ (x & 7)) * 8];
            oacc[0][dt] = __builtin_amdgcn_mfma_f32_16x16x32_bf16(
                vf, pack4(pbq[0][c][0], pbq[0][c][1], pbq[0][c][2], pbq[0][c][3]), oacc[0][dt], 0, 0, 0);
            oacc[1][dt] = __builtin_amdgcn_mfma_f32_16x16x32_bf16(
                vf, pack4(pbq[1][c][0], pbq[1][c][1], pbq[1][c][2], pbq[1][c][3]), oacc[1][dt], 0, 0, 0);
          }
        __builtin_amdgcn_s_setprio(0);
      }

      __syncthreads();   // next tile landed (implicit vmcnt drain) + LDS reads done
      cur ^= 1;
    }

    // ---- epilogue for this item ----
    const int b = bh >> 4, h = bh & 15;
#pragma unroll
    for (int qs = 0; qs < 2; ++qs) {
      float ls = lrun[qs];
      ls += __shfl_xor(ls, 16);
      ls += __shfl_xor(ls, 32);
      float inv = 1.0f / ls;
      int tok = qbase + w * 32 + qs * 16 + x;
#pragma unroll
      for (int dt = 0; dt < 4; ++dt) {
        uint2 uu;
        uu.x = cvtpk(oacc[qs][dt][0] * inv, oacc[qs][dt][1] * inv);
        uu.y = cvtpk(oacc[qs][dt][2] * inv, oacc[qs][dt][3] * inv);
        *(uint2*)&ctx[(size_t)(b * S + tok) * D + h * 64 + dt * 16 + 4 * g] = uu;
      }
    }
  }
}

extern "C" void kernel_launch(void* const* d_in, const int* in_sizes, int n_in,
                              void* d_out, int out_size, void* d_ws, size_t ws_size,
                              hipStream_t stream) {
  const float* x  = (const float*)d_in[0];
  const float* Wq = (const float*)d_in[1];
  const float* Wk = (const float*)d_in[2];
  const float* Wv = (const float*)d_in[3];
  const float* Wo = (const float*)d_in[4];
  const float* bo = (const float*)d_in[5];
  float* out = (float*)d_out;

  if (ws_size < (size_t)120 * 1024 * 1024) return;

  char* ws = (char*)d_ws;
  const size_t MB = 1024 * 1024;
  ushort* xcat = (ushort*)(ws);              // 32MB; ctx aliases low 16MB (xcat dead after QKV)
  ushort* ctx  = (ushort*)(ws);
  u32*    ctr  = (u32*)(ws + 31 * MB);       // in xcat's tail; memset after QKV gemms
  ushort* wcat = (ushort*)(ws + 32 * MB);    // 6MB [3072][1024]
  ushort* wob  = (ushort*)(ws + 38 * MB);    // 2MB
  ushort* qhi  = (ushort*)(ws + 40 * MB);    // 16MB each
  ushort* qlo  = (ushort*)(ws + 56 * MB);
  ushort* khi  = (ushort*)(ws + 72 * MB);
  ushort* klo  = (ushort*)(ws + 88 * MB);
  ushort* vt   = (ushort*)(ws + 104 * MB);

  prep_x<<<2048, 256, 0, stream>>>(x, xcat);
  prep_w<<<1024, 256, 0, stream>>>(Wq, Wk, Wv, Wo, wcat, wob);

  // Q,K: hi/lo (K=2048). V: single-precision path (K=1024, reads x_hi via stride 2048).
  gemm97<0, 2048, 1024, 2048><<<dim3(64, 16), 256, 0, stream>>>(
      xcat, wcat, qhi, qlo, khi, klo, nullptr, nullptr, nullptr);
  gemm97<1, 1024, 1024, 2048><<<dim3(64, 8), 256, 0, stream>>>(
      xcat, wcat + 2 * D * D, nullptr, nullptr, nullptr, nullptr, vt, nullptr, nullptr);

  hipMemsetAsync(ctr, 0, sizeof(u32), stream);   // reset work queue each launch

  flash13<<<768, 256, 0, stream>>>(qhi, qlo, khi, klo, vt, ctx, ctr);

  gemm97<2, 1024, 1024, 1024><<<dim3(64, 8), 256, 0, stream>>>(
      ctx, wob, nullptr, nullptr, nullptr, nullptr, nullptr, out, bo);
}

// Round 14
// 324.305 us; speedup vs baseline: 1.0479x; 1.0479x over previous
//
#include <hip/hip_runtime.h>
#include <hip/hip_bf16.h>
#include <cstdint>
#include <cstddef>

#define S 4096
#define D 1024
#define H 16
#define HD 64
#define BATCH 2
#define M_TOK 8192   // BATCH*S
#define K2 2048

typedef short short8 __attribute__((ext_vector_type(8)));
typedef __bf16 bf16x8 __attribute__((ext_vector_type(8)));
typedef float f32x4 __attribute__((ext_vector_type(4)));
typedef unsigned int u32;

static __device__ __forceinline__ ushort f2bf(float f) {
  union { float f; uint32_t u; } v; v.f = f;
  uint32_t u = v.u + 0x7FFFu + ((v.u >> 16) & 1u);
  return (ushort)(u >> 16);
}
static __device__ __forceinline__ float bf2f(ushort h) {
  union { uint32_t u; float f; } v; v.u = ((uint32_t)h) << 16; return v.f;
}
static __device__ __forceinline__ uint32_t cvtpk(float lo, float hi) {
  uint32_t r;
  asm("v_cvt_pk_bf16_f32 %0, %1, %2" : "=v"(r) : "v"(lo), "v"(hi));
  return r;
}
static __device__ __forceinline__ float vexp2(float x) {
  float r;
  asm("v_exp_f32 %0, %1" : "=v"(r) : "v"(x));
  return r;
}
static __device__ __forceinline__ bf16x8 pack4(uint32_t a, uint32_t b, uint32_t c, uint32_t d) {
  union { uint32_t u[4]; bf16x8 v; } z;
  z.u[0] = a; z.u[1] = b; z.u[2] = c; z.u[3] = d;
  return z.v;
}
// async global->LDS, 16B per lane; LDS dest = wave-uniform base + lane*16
static __device__ __forceinline__ void gld16(const void* g, void* l) {
  __builtin_amdgcn_global_load_lds(
      (const __attribute__((address_space(1))) u32*)g,
      (__attribute__((address_space(3))) u32*)l, 16, 0, 0);
}
static __device__ __forceinline__ ushort sgn(float a) {
  return a > 0.f ? 0x3F80 : (a < 0.f ? 0xBF80 : 0);
}

// ---------------- prep: x -> [hi|lo] bf16 concat (vectorized) ----------------
__global__ void prep_x(const float* __restrict__ x, ushort* __restrict__ xcat) {
  int i = blockIdx.x * blockDim.x + threadIdx.x;
  const int total = M_TOK * 128;   // groups of 8 floats
  for (; i < total; i += gridDim.x * blockDim.x) {
    int row = i >> 7, c8 = (i & 127) * 8;
    const float* px = &x[(size_t)row * 1024 + c8];
    float4 a = *(const float4*)px;
    float4 b = *(const float4*)(px + 4);
    float va[8] = {a.x, a.y, a.z, a.w, b.x, b.y, b.z, b.w};
    union { ushort u[8]; short8 v; } Hh, Ll;
#pragma unroll
    for (int j = 0; j < 8; ++j) {
      ushort h = f2bf(va[j]);
      Hh.u[j] = h;
      Ll.u[j] = f2bf(va[j] - bf2f(h));
    }
    *(short8*)&xcat[(size_t)row * K2 + c8] = Hh.v;
    *(short8*)&xcat[(size_t)row * K2 + 1024 + c8] = Ll.v;
  }
}

// W -> sign(W) bf16; Wq/Wk/Wv concat rows [3072][1024]; Wo separate
__global__ void prep_w(const float* __restrict__ wq, const float* __restrict__ wk,
                       const float* __restrict__ wv, const float* __restrict__ wo,
                       ushort* __restrict__ wcat, ushort* __restrict__ wob) {
  int i = blockIdx.x * blockDim.x + threadIdx.x;
  const int total = (D * D) / 4;
  for (; i < total; i += gridDim.x * blockDim.x) {
    float4 a;
    union { ushort u[4]; uint2 v; } t;
    a = *(const float4*)&wq[i * 4];
    t.u[0] = sgn(a.x); t.u[1] = sgn(a.y); t.u[2] = sgn(a.z); t.u[3] = sgn(a.w);
    *(uint2*)&wcat[i * 4] = t.v;
    a = *(const float4*)&wk[i * 4];
    t.u[0] = sgn(a.x); t.u[1] = sgn(a.y); t.u[2] = sgn(a.z); t.u[3] = sgn(a.w);
    *(uint2*)&wcat[D * D + i * 4] = t.v;
    a = *(const float4*)&wv[i * 4];
    t.u[0] = sgn(a.x); t.u[1] = sgn(a.y); t.u[2] = sgn(a.z); t.u[3] = sgn(a.w);
    *(uint2*)&wcat[2 * D * D + i * 4] = t.v;
    a = *(const float4*)&wo[i * 4];
    t.u[0] = sgn(a.x); t.u[1] = sgn(a.y); t.u[2] = sgn(a.z); t.u[3] = sgn(a.w);
    *(uint2*)&wob[i * 4] = t.v;
  }
}

// ---------------- gemm256: 256x256 tile, BK=32, 3-buffer counted-vmcnt pipeline (T3+T4) ----------------
// C = A[8192][2048] * B^T (B rows wrap at 1024). Q/K hi-lo epilogue (proj = colg>>10).
// 8 waves (2m x 4n); 32 MFMA per barrier; stage issued POST-barrier (target buffer was
// consumed two barriers ago -> race-free); vmcnt(4) keeps next tile's loads in flight.
__global__ __launch_bounds__(512, 2) void gemm256(
    const ushort* __restrict__ A, const ushort* __restrict__ Bw,
    ushort* __restrict__ q_hi, ushort* __restrict__ q_lo,
    ushort* __restrict__ k_hi, ushort* __restrict__ k_lo)
{
  __shared__ ushort smA[3][256 * 32];
  __shared__ ushort smB[3][256 * 32];
  const int tid = threadIdx.x;
  const int l = tid & 63;
  const int w = tid >> 6;          // 0..7
  const int x = l & 15, g = l >> 4;
  const int wm = w >> 2, wn = w & 3;
  const int bm = blockIdx.x, bn = blockIdx.y;

  // staging: round r chunk q=r*512+tid -> (row=q>>2, blk=q&3); source pre-swizzled by
  // sw(row) = (row&3)^((row>>2)&3) so reader's XOR'd column lands linear.
  const ushort* gA[2]; const ushort* gB[2]; int ldso[2];
#pragma unroll
  for (int r = 0; r < 2; ++r) {
    int q = r * 512 + tid;
    int row = q >> 2;
    int blk = (q & 3) ^ ((row & 3) ^ ((row >> 2) & 3));
    gA[r] = &A[(size_t)(bm * 256 + row) * 2048 + blk * 8];
    gB[r] = &Bw[(size_t)(bn * 256 + row) * 1024 + blk * 8];
    ldso[r] = (r * 512 + w * 64) * 8;
  }

  f32x4 acc[8][4] = {};

  // prologue: stage K-tiles 0,1 into bufs 0,1
#pragma unroll
  for (int r = 0; r < 2; ++r) {
    gld16(gA[r] + 0, &smA[0][ldso[r]]);
    gld16(gB[r] + 0, &smB[0][ldso[r]]);
  }
#pragma unroll
  for (int r = 0; r < 2; ++r) {
    gld16(gA[r] + 32, &smA[1][ldso[r]]);
    gld16(gB[r] + ((32) & 1023), &smB[1][ldso[r]]);
  }

  const int swz = (x & 3) ^ ((x >> 2) & 3);
  int cb = 0;
  for (int s = 0; s < 64; ++s) {
    // tile s landed? (tile s+1's 4 loads may stay in flight)
    if (s < 63) {
      asm volatile("s_waitcnt vmcnt(4)" ::: "memory");
    } else {
      asm volatile("s_waitcnt vmcnt(0)" ::: "memory");
    }
    __builtin_amdgcn_s_barrier();   // all waves: tile s ready, tile (s-1) fully consumed

    // post-barrier: issue stage of tile s+2 into buf (cb+2)%3 (consumed at iter s-1)
    if (s + 2 < 64) {
      int nb = cb - 1; if (nb < 0) nb = 2;   // (cb+2)%3
      int k0 = (s + 2) * 32;
#pragma unroll
      for (int r = 0; r < 2; ++r) {
        gld16(gA[r] + k0, &smA[nb][ldso[r]]);
        gld16(gB[r] + (k0 & 1023), &smB[nb][ldso[r]]);
      }
    }

    const ushort* bA = smA[cb];
    const ushort* bB = smB[cb];
    bf16x8 af[8], bf_[4];
#pragma unroll
    for (int m = 0; m < 8; ++m)
      af[m] = *(const bf16x8*)&bA[(wm * 128 + m * 16 + x) * 32 + (g ^ swz) * 8];
#pragma unroll
    for (int n = 0; n < 4; ++n)
      bf_[n] = *(const bf16x8*)&bB[(wn * 64 + n * 16 + x) * 32 + (g ^ swz) * 8];

    __builtin_amdgcn_s_setprio(1);
#pragma unroll
    for (int m = 0; m < 8; ++m)
#pragma unroll
      for (int n = 0; n < 4; ++n)
        acc[m][n] = __builtin_amdgcn_mfma_f32_16x16x32_bf16(af[m], bf_[n], acc[m][n], 0, 0, 0);
    __builtin_amdgcn_s_setprio(0);

    cb = (cb == 2) ? 0 : cb + 1;
  }

  // epilogue: Q/K hi+lo (proj by output column)
#pragma unroll
  for (int m = 0; m < 8; ++m)
#pragma unroll
    for (int n = 0; n < 4; ++n)
#pragma unroll
      for (int r = 0; r < 4; ++r) {
        int rowg = bm * 256 + wm * 128 + m * 16 + g * 4 + r;
        int colg = bn * 256 + wn * 64 + n * 16 + x;
        float v = acc[m][n][r];
        int bi = rowg >> 12, ntok = rowg & 4095;
        int proj = colg >> 10;
        int cg = colg & 1023;
        int h = cg >> 6, hd = cg & 63;
        ushort* oh = (proj == 0) ? q_hi : k_hi;
        ushort* ol = (proj == 0) ? q_lo : k_lo;
        size_t off = (size_t)(bi * H + h) * (S * HD) + (size_t)ntok * HD + hd;
        ushort hiv = f2bf(v);
        oh[off] = hiv;
        ol[off] = f2bf(v - bf2f(hiv));
      }
}

// ---------------- GEMM (m97 structure): C = A (M x KK @ stride AST) * B^T; B rows wrap at BROW ----------------
// EPI 1: V^T permuted epilogue. EPI 2: fp32 + bias.
template<int EPI, int KK, int BROW, int AST>
__global__ __launch_bounds__(256) void gemm97(
    const ushort* __restrict__ A, const ushort* __restrict__ Bw,
    ushort* __restrict__ v_t,
    float* __restrict__ of, const float* __restrict__ bias)
{
  __shared__ ushort smA[128 * 32];
  __shared__ ushort smB[128 * 32];
  const int tid = threadIdx.x;
  const int l = tid & 63;
  const int w = tid >> 6;
  const int x = l & 15, g = l >> 4;
  const int wm = w >> 1, wn = w & 1;
  const int bm = blockIdx.x, bn = blockIdx.y;

  const ushort* gA[2]; const ushort* gB[2]; int ldso[2];
#pragma unroll
  for (int p = 0; p < 2; ++p) {
    int q = p * 256 + tid;
    gA[p] = &A[(size_t)(bm * 128 + (q >> 2)) * AST + (q & 3) * 8];
    gB[p] = &Bw[(size_t)(bn * 128 + (q >> 2)) * BROW + (q & 3) * 8];
    ldso[p] = (p * 256 + w * 64) * 8;
  }

  f32x4 acc[4][4] = {};

  for (int k0 = 0; k0 < KK; k0 += 32) {
    __syncthreads();
#pragma unroll
    for (int p = 0; p < 2; ++p) {
      gld16(gA[p] + k0, &smA[ldso[p]]);
      gld16(gB[p] + (k0 & (BROW - 1)), &smB[ldso[p]]);
    }
    __syncthreads();
    bf16x8 af[4], bf_[4];
#pragma unroll
    for (int m = 0; m < 4; ++m)
      af[m] = *(const bf16x8*)&smA[(wm * 64 + m * 16 + x) * 32 + g * 8];
#pragma unroll
    for (int n = 0; n < 4; ++n)
      bf_[n] = *(const bf16x8*)&smB[(wn * 64 + n * 16 + x) * 32 + g * 8];
#pragma unroll
    for (int m = 0; m < 4; ++m)
#pragma unroll
      for (int n = 0; n < 4; ++n)
        acc[m][n] = __builtin_amdgcn_mfma_f32_16x16x32_bf16(af[m], bf_[n], acc[m][n], 0, 0, 0);
  }

#pragma unroll
  for (int m = 0; m < 4; ++m)
#pragma unroll
    for (int n = 0; n < 4; ++n)
#pragma unroll
      for (int r = 0; r < 4; ++r) {
        int rowg = bm * 128 + wm * 64 + m * 16 + g * 4 + r;
        int colg = bn * 128 + wn * 64 + n * 16 + x;
        float v = acc[m][n][r];
        if (EPI == 2) {
          of[(size_t)rowg * D + colg] = v + bias[colg];
        } else {
          int bi = rowg >> 12, ntok = rowg & 4095;
          int cg = colg & 1023;
          int h = cg >> 6, hd = cg & 63;
          size_t bhb = (size_t)(bi * H + h) * (S * HD);
          // V^T with within-32-token permutation matching MFMA k-slots: t=16b+4g+r -> 8g+4b+r
          int t5 = ntok & 31;
          int pos = ((t5 >> 2) & 3) * 8 + ((t5 >> 4) & 1) * 4 + (t5 & 3);
          v_t[bhb + (size_t)hd * S + (ntok & ~31) + pos] = f2bf(v);
        }
      }
}

// ---------------- flash5 (best flash: 195.6us) ----------------
__global__ __launch_bounds__(256) void flash5(
    const ushort* __restrict__ qhi, const ushort* __restrict__ qlo,
    const ushort* __restrict__ khi, const ushort* __restrict__ klo,
    const ushort* __restrict__ vt, ushort* __restrict__ ctx)
{
  __shared__ ushort smKhi[2][64 * 64];
  __shared__ ushort smKlo[2][64 * 64];
  __shared__ ushort smVT[2][64 * 64];

  const int tid = threadIdx.x;
  const int l = tid & 63;
  const int w = tid >> 6;
  const int x = l & 15;
  const int g = l >> 4;
  const int bh = blockIdx.x;
  const int qt = (int)(gridDim.y - 1) - (int)blockIdx.y;   // heavy tiles first
  const int qbase = qt * 128;
  const size_t qkbase = (size_t)bh * S * HD;

  int soff_k[2]; size_t soff_v[2]; int ldso[2];
#pragma unroll
  for (int p = 0; p < 2; ++p) {
    int q = p * 256 + tid;
    int r2 = q >> 3;
    int sb = (q & 7) ^ (r2 & 7);
    soff_k[p] = r2 * HD + sb * 8;
    soff_v[p] = (size_t)r2 * S + sb * 8;
    ldso[p] = (p * 256 + w * 64) * 8;
  }
  const ushort* khb = khi + qkbase;
  const ushort* klb = klo + qkbase;
  const ushort* vtb = vt + qkbase;

  bf16x8 bq[2][2][2];
#pragma unroll
  for (int qs = 0; qs < 2; ++qs) {
    int qrow = qbase + w * 32 + qs * 16 + x;
    size_t base = qkbase + (size_t)qrow * HD + g * 8;
    bq[qs][0][0] = *(const bf16x8*)&qhi[base];
    bq[qs][0][1] = *(const bf16x8*)&qhi[base + 32];
    bq[qs][1][0] = *(const bf16x8*)&qlo[base];
    bq[qs][1][1] = *(const bf16x8*)&qlo[base + 32];
  }

  float mrun[2] = {-1e30f, -1e30f};
  float lrun[2] = {0.f, 0.f};   // lane-partial; reduced at epilogue
  f32x4 oacc[2][4] = {};

  const int kvmax = (qbase + 127) >> 6;
  const int qmaxw = qbase + w * 32 + 31;
  const float C1 = 0.125f * 1.44269504f;
  const float TH = 8.0f / C1;

#pragma unroll
  for (int p = 0; p < 2; ++p) {
    gld16(khb + soff_k[p], &smKhi[0][ldso[p]]);
    gld16(klb + soff_k[p], &smKlo[0][ldso[p]]);
    gld16(vtb + soff_v[p], &smVT[0][ldso[p]]);
  }
  __syncthreads();

  int cur = 0;
  for (int kv = 0; kv <= kvmax; ++kv) {
    if (kv < kvmax) {
      const ushort* kh = khb + (size_t)(kv + 1) * (64 * HD);
      const ushort* kl = klb + (size_t)(kv + 1) * (64 * HD);
      const ushort* vp = vtb + (size_t)(kv + 1) * 64;
      int nb = cur ^ 1;
#pragma unroll
      for (int p = 0; p < 2; ++p) {
        gld16(kh + soff_k[p], &smKhi[nb][ldso[p]]);
        gld16(kl + soff_k[p], &smKlo[nb][ldso[p]]);
        gld16(vp + soff_v[p], &smVT[nb][ldso[p]]);
      }
    }

    if (kv * 64 <= qmaxw) {
      const ushort* bKhi = smKhi[cur];
      const ushort* bKlo = smKlo[cur];
      const ushort* bVT = smVT[cur];

      f32x4 scq[2][4];
      __builtin_amdgcn_s_setprio(1);
#pragma unroll
      for (int t = 0; t < 4; ++t) {
        f32x4 a0 = {}, a1 = {};
#pragma unroll
        for (int c = 0; c < 2; ++c) {
          int pb = (t * 16 + x) * 64 + ((4 * c + g) ^ (x & 7)) * 8;
          bf16x8 kH = *(const bf16x8*)&bKhi[pb];
          bf16x8 kL = *(const bf16x8*)&bKlo[pb];
          a0 = __builtin_amdgcn_mfma_f32_16x16x32_bf16(kH, bq[0][0][c], a0, 0, 0, 0);
          a0 = __builtin_amdgcn_mfma_f32_16x16x32_bf16(kL, bq[0][0][c], a0, 0, 0, 0);
          a0 = __builtin_amdgcn_mfma_f32_16x16x32_bf16(kH, bq[0][1][c], a0, 0, 0, 0);
          a1 = __builtin_amdgcn_mfma_f32_16x16x32_bf16(kH, bq[1][0][c], a1, 0, 0, 0);
          a1 = __builtin_amdgcn_mfma_f32_16x16x32_bf16(kL, bq[1][0][c], a1, 0, 0, 0);
          a1 = __builtin_amdgcn_mfma_f32_16x16x32_bf16(kH, bq[1][1][c], a1, 0, 0, 0);
        }
        scq[0][t] = a0; scq[1][t] = a1;
      }
      __builtin_amdgcn_s_setprio(0);

      const bool needmask = (kv * 64 + 63 > qbase + w * 32);
      uint32_t pbq[2][2][4];

#pragma unroll
      for (int qs = 0; qs < 2; ++qs) {
        if (needmask) {
          int qglob = qbase + w * 32 + qs * 16 + x;
          int kb = kv * 64 + 4 * g;
#pragma unroll
          for (int t = 0; t < 4; ++t)
#pragma unroll
            for (int r = 0; r < 4; ++r)
              if (kb + t * 16 + r > qglob) scq[qs][t][r] = -1e30f;
        }
        float mt[4];
#pragma unroll
        for (int t = 0; t < 4; ++t)
          mt[t] = fmaxf(fmaxf(scq[qs][t][0], scq[qs][t][1]),
                        fmaxf(scq[qs][t][2], scq[qs][t][3]));
        float mloc = fmaxf(fmaxf(mt[0], mt[1]), fmaxf(mt[2], mt[3]));
        if (__any(mloc > mrun[qs] + TH)) {
          mloc = fmaxf(mloc, __shfl_xor(mloc, 16));
          mloc = fmaxf(mloc, __shfl_xor(mloc, 32));
          float mnew = fmaxf(mrun[qs], mloc);
          float scal = vexp2((mrun[qs] - mnew) * C1);
          mrun[qs] = mnew;
          lrun[qs] *= scal;
#pragma unroll
          for (int dt = 0; dt < 4; ++dt) oacc[qs][dt] *= scal;
        }
        float mc = mrun[qs] * C1;
#pragma unroll
        for (int t = 0; t < 4; ++t)
#pragma unroll
          for (int r = 0; r < 4; ++r)
            scq[qs][t][r] = vexp2(scq[qs][t][r] * C1 - mc);
        float st[4];
#pragma unroll
        for (int t = 0; t < 4; ++t)
          st[t] = (scq[qs][t][0] + scq[qs][t][1]) + (scq[qs][t][2] + scq[qs][t][3]);
        lrun[qs] += (st[0] + st[1]) + (st[2] + st[3]);
#pragma unroll
        for (int c = 0; c < 2; ++c) {
          pbq[qs][c][0] = cvtpk(scq[qs][2 * c][0], scq[qs][2 * c][1]);
          pbq[qs][c][1] = cvtpk(scq[qs][2 * c][2], scq[qs][2 * c][3]);
          pbq[qs][c][2] = cvtpk(scq[qs][2 * c + 1][0], scq[qs][2 * c + 1][1]);
          pbq[qs][c][3] = cvtpk(scq[qs][2 * c + 1][2], scq[qs][2 * c + 1][3]);
        }
      }

      __builtin_amdgcn_s_setprio(1);
#pragma unroll
      for (int c = 0; c < 2; ++c)
#pragma unroll
        for (int dt = 0; dt < 4; ++dt) {
          bf16x8 vf = *(const bf16x8*)&bVT[(dt * 16 + x) * 64 + ((4 * c + g) ^ (x & 7)) * 8];
          oacc[0][dt] = __builtin_amdgcn_mfma_f32_16x16x32_bf16(
              vf, pack4(pbq[0][c][0], pbq[0][c][1], pbq[0][c][2], pbq[0][c][3]), oacc[0][dt], 0, 0, 0);
          oacc[1][dt] = __builtin_amdgcn_mfma_f32_16x16x32_bf16(
              vf, pack4(pbq[1][c][0], pbq[1][c][1], pbq[1][c][2], pbq[1][c][3]), oacc[1][dt], 0, 0, 0);
        }
      __builtin_amdgcn_s_setprio(0);
    }

    __syncthreads();
    cur ^= 1;
  }

  const int b = bh >> 4, h = bh & 15;
#pragma unroll
  for (int qs = 0; qs < 2; ++qs) {
    float ls = lrun[qs];
    ls += __shfl_xor(ls, 16);
    ls += __shfl_xor(ls, 32);
    float inv = 1.0f / ls;
    int tok = qbase + w * 32 + qs * 16 + x;
#pragma unroll
    for (int dt = 0; dt < 4; ++dt) {
      uint2 uu;
      uu.x = cvtpk(oacc[qs][dt][0] * inv, oacc[qs][dt][1] * inv);
      uu.y = cvtpk(oacc[qs][dt][2] * inv, oacc[qs][dt][3] * inv);
      *(uint2*)&ctx[(size_t)(b * S + tok) * D + h * 64 + dt * 16 + 4 * g] = uu;
    }
  }
}

extern "C" void kernel_launch(void* const* d_in, const int* in_sizes, int n_in,
                              void* d_out, int out_size, void* d_ws, size_t ws_size,
                              hipStream_t stream) {
  const float* x  = (const float*)d_in[0];
  const float* Wq = (const float*)d_in[1];
  const float* Wk = (const float*)d_in[2];
  const float* Wv = (const float*)d_in[3];
  const float* Wo = (const float*)d_in[4];
  const float* bo = (const float*)d_in[5];
  float* out = (float*)d_out;

  if (ws_size < (size_t)120 * 1024 * 1024) return;

  char* ws = (char*)d_ws;
  const size_t MB = 1024 * 1024;
  ushort* xcat = (ushort*)(ws);              // 32MB; ctx aliases (xcat dead after projections)
  ushort* ctx  = (ushort*)(ws);
  ushort* wcat = (ushort*)(ws + 32 * MB);    // 6MB [3072][1024]
  ushort* wob  = (ushort*)(ws + 38 * MB);    // 2MB
  ushort* qhi  = (ushort*)(ws + 40 * MB);    // 16MB each
  ushort* qlo  = (ushort*)(ws + 56 * MB);
  ushort* khi  = (ushort*)(ws + 72 * MB);
  ushort* klo  = (ushort*)(ws + 88 * MB);
  ushort* vt   = (ushort*)(ws + 104 * MB);

  prep_x<<<2048, 256, 0, stream>>>(x, xcat);
  prep_w<<<1024, 256, 0, stream>>>(Wq, Wk, Wv, Wo, wcat, wob);

  // Q,K: 256^2 counted-vmcnt pipeline (K=2048 over hi|lo, B rows wrap at 1024).
  gemm256<<<dim3(32, 8), 512, 0, stream>>>(xcat, wcat, qhi, qlo, khi, klo);
  // V: single-precision path (K=1024, reads x_hi via stride 2048), 128^2 m97 structure.
  gemm97<1, 1024, 1024, 2048><<<dim3(64, 8), 256, 0, stream>>>(
      xcat, wcat + 2 * D * D, vt, nullptr, nullptr);

  flash5<<<dim3(BATCH * H, S / 128), 256, 0, stream>>>(qhi, qlo, khi, klo, vt, ctx);

  gemm97<2, 1024, 1024, 1024><<<dim3(64, 8), 256, 0, stream>>>(
      ctx, wob, nullptr, out, bo);
}

// Round 15
// 321.039 us; speedup vs baseline: 1.0585x; 1.0102x over previous
//
#include <hip/hip_runtime.h>
#include <hip/hip_bf16.h>
#include <cstdint>
#include <cstddef>

#define S 4096
#define D 1024
#define H 16
#define HD 64
#define BATCH 2
#define M_TOK 8192   // BATCH*S
#define K2 2048

typedef short short8 __attribute__((ext_vector_type(8)));
typedef __bf16 bf16x8 __attribute__((ext_vector_type(8)));
typedef float f32x4 __attribute__((ext_vector_type(4)));
typedef float f32x16 __attribute__((ext_vector_type(16)));
typedef unsigned int u32;

static __device__ __forceinline__ ushort f2bf(float f) {
  union { float f; uint32_t u; } v; v.f = f;
  uint32_t u = v.u + 0x7FFFu + ((v.u >> 16) & 1u);
  return (ushort)(u >> 16);
}
static __device__ __forceinline__ float bf2f(ushort h) {
  union { uint32_t u; float f; } v; v.u = ((uint32_t)h) << 16; return v.f;
}
static __device__ __forceinline__ uint32_t cvtpk(float lo, float hi) {
  uint32_t r;
  asm("v_cvt_pk_bf16_f32 %0, %1, %2" : "=v"(r) : "v"(lo), "v"(hi));
  return r;
}
static __device__ __forceinline__ float vexp2(float x) {
  float r;
  asm("v_exp_f32 %0, %1" : "=v"(r) : "v"(x));
  return r;
}
static __device__ __forceinline__ bf16x8 pack4(uint32_t a, uint32_t b, uint32_t c, uint32_t d) {
  union { uint32_t u[4]; bf16x8 v; } z;
  z.u[0] = a; z.u[1] = b; z.u[2] = c; z.u[3] = d;
  return z.v;
}
// async global->LDS, 16B per lane; LDS dest = wave-uniform base + lane*16
static __device__ __forceinline__ void gld16(const void* g, void* l) {
  __builtin_amdgcn_global_load_lds(
      (const __attribute__((address_space(1))) u32*)g,
      (__attribute__((address_space(3))) u32*)l, 16, 0, 0);
}
static __device__ __forceinline__ ushort sgn(float a) {
  return a > 0.f ? 0x3F80 : (a < 0.f ? 0xBF80 : 0);
}

// ---------------- prep: x -> [hi|lo] bf16 concat (vectorized) ----------------
__global__ void prep_x(const float* __restrict__ x, ushort* __restrict__ xcat) {
  int i = blockIdx.x * blockDim.x + threadIdx.x;
  const int total = M_TOK * 128;   // groups of 8 floats
  for (; i < total; i += gridDim.x * blockDim.x) {
    int row = i >> 7, c8 = (i & 127) * 8;
    const float* px = &x[(size_t)row * 1024 + c8];
    float4 a = *(const float4*)px;
    float4 b = *(const float4*)(px + 4);
    float va[8] = {a.x, a.y, a.z, a.w, b.x, b.y, b.z, b.w};
    union { ushort u[8]; short8 v; } Hh, Ll;
#pragma unroll
    for (int j = 0; j < 8; ++j) {
      ushort h = f2bf(va[j]);
      Hh.u[j] = h;
      Ll.u[j] = f2bf(va[j] - bf2f(h));
    }
    *(short8*)&xcat[(size_t)row * K2 + c8] = Hh.v;
    *(short8*)&xcat[(size_t)row * K2 + 1024 + c8] = Ll.v;
  }
}

// W -> sign(W) bf16; Wq/Wk/Wv concat rows [3072][1024]; Wo separate
__global__ void prep_w(const float* __restrict__ wq, const float* __restrict__ wk,
                       const float* __restrict__ wv, const float* __restrict__ wo,
                       ushort* __restrict__ wcat, ushort* __restrict__ wob) {
  int i = blockIdx.x * blockDim.x + threadIdx.x;
  const int total = (D * D) / 4;
  for (; i < total; i += gridDim.x * blockDim.x) {
    float4 a;
    union { ushort u[4]; uint2 v; } t;
    a = *(const float4*)&wq[i * 4];
    t.u[0] = sgn(a.x); t.u[1] = sgn(a.y); t.u[2] = sgn(a.z); t.u[3] = sgn(a.w);
    *(uint2*)&wcat[i * 4] = t.v;
    a = *(const float4*)&wk[i * 4];
    t.u[0] = sgn(a.x); t.u[1] = sgn(a.y); t.u[2] = sgn(a.z); t.u[3] = sgn(a.w);
    *(uint2*)&wcat[D * D + i * 4] = t.v;
    a = *(const float4*)&wv[i * 4];
    t.u[0] = sgn(a.x); t.u[1] = sgn(a.y); t.u[2] = sgn(a.z); t.u[3] = sgn(a.w);
    *(uint2*)&wcat[2 * D * D + i * 4] = t.v;
    a = *(const float4*)&wo[i * 4];
    t.u[0] = sgn(a.x); t.u[1] = sgn(a.y); t.u[2] = sgn(a.z); t.u[3] = sgn(a.w);
    *(uint2*)&wob[i * 4] = t.v;
  }
}

// ---------------- gemm256: 256x256 tile, BK=32, 3-buffer counted-vmcnt pipeline (T3+T4) ----------------
__global__ __launch_bounds__(512, 2) void gemm256(
    const ushort* __restrict__ A, const ushort* __restrict__ Bw,
    ushort* __restrict__ q_hi, ushort* __restrict__ q_lo,
    ushort* __restrict__ k_hi, ushort* __restrict__ k_lo)
{
  __shared__ ushort smA[3][256 * 32];
  __shared__ ushort smB[3][256 * 32];
  const int tid = threadIdx.x;
  const int l = tid & 63;
  const int w = tid >> 6;          // 0..7
  const int x = l & 15, g = l >> 4;
  const int wm = w >> 2, wn = w & 3;
  const int bm = blockIdx.x, bn = blockIdx.y;

  const ushort* gA[2]; const ushort* gB[2]; int ldso[2];
#pragma unroll
  for (int r = 0; r < 2; ++r) {
    int q = r * 512 + tid;
    int row = q >> 2;
    int blk = (q & 3) ^ ((row & 3) ^ ((row >> 2) & 3));
    gA[r] = &A[(size_t)(bm * 256 + row) * 2048 + blk * 8];
    gB[r] = &Bw[(size_t)(bn * 256 + row) * 1024 + blk * 8];
    ldso[r] = (r * 512 + w * 64) * 8;
  }

  f32x4 acc[8][4] = {};

#pragma unroll
  for (int r = 0; r < 2; ++r) {
    gld16(gA[r] + 0, &smA[0][ldso[r]]);
    gld16(gB[r] + 0, &smB[0][ldso[r]]);
  }
#pragma unroll
  for (int r = 0; r < 2; ++r) {
    gld16(gA[r] + 32, &smA[1][ldso[r]]);
    gld16(gB[r] + ((32) & 1023), &smB[1][ldso[r]]);
  }

  const int swz = (x & 3) ^ ((x >> 2) & 3);
  int cb = 0;
  for (int s = 0; s < 64; ++s) {
    if (s < 63) {
      asm volatile("s_waitcnt vmcnt(4)" ::: "memory");
    } else {
      asm volatile("s_waitcnt vmcnt(0)" ::: "memory");
    }
    __builtin_amdgcn_s_barrier();

    if (s + 2 < 64) {
      int nb = cb - 1; if (nb < 0) nb = 2;
      int k0 = (s + 2) * 32;
#pragma unroll
      for (int r = 0; r < 2; ++r) {
        gld16(gA[r] + k0, &smA[nb][ldso[r]]);
        gld16(gB[r] + (k0 & 1023), &smB[nb][ldso[r]]);
      }
    }

    const ushort* bA = smA[cb];
    const ushort* bB = smB[cb];
    bf16x8 af[8], bf_[4];
#pragma unroll
    for (int m = 0; m < 8; ++m)
      af[m] = *(const bf16x8*)&bA[(wm * 128 + m * 16 + x) * 32 + (g ^ swz) * 8];
#pragma unroll
    for (int n = 0; n < 4; ++n)
      bf_[n] = *(const bf16x8*)&bB[(wn * 64 + n * 16 + x) * 32 + (g ^ swz) * 8];

    __builtin_amdgcn_s_setprio(1);
#pragma unroll
    for (int m = 0; m < 8; ++m)
#pragma unroll
      for (int n = 0; n < 4; ++n)
        acc[m][n] = __builtin_amdgcn_mfma_f32_16x16x32_bf16(af[m], bf_[n], acc[m][n], 0, 0, 0);
    __builtin_amdgcn_s_setprio(0);

    cb = (cb == 2) ? 0 : cb + 1;
  }

#pragma unroll
  for (int m = 0; m < 8; ++m)
#pragma unroll
    for (int n = 0; n < 4; ++n)
#pragma unroll
      for (int r = 0; r < 4; ++r) {
        int rowg = bm * 256 + wm * 128 + m * 16 + g * 4 + r;
        int colg = bn * 256 + wn * 64 + n * 16 + x;
        float v = acc[m][n][r];
        int bi = rowg >> 12, ntok = rowg & 4095;
        int proj = colg >> 10;
        int cg = colg & 1023;
        int h = cg >> 6, hd = cg & 63;
        ushort* oh = (proj == 0) ? q_hi : k_hi;
        ushort* ol = (proj == 0) ? q_lo : k_lo;
        size_t off = (size_t)(bi * H + h) * (S * HD) + (size_t)ntok * HD + hd;
        ushort hiv = f2bf(v);
        oh[off] = hiv;
        ol[off] = f2bf(v - bf2f(hiv));
      }
}

// ---------------- GEMM (m97): EPI 1: V^T plain transpose epilogue. EPI 2: fp32 + bias. ----------------
template<int EPI, int KK, int BROW, int AST>
__global__ __launch_bounds__(256) void gemm97(
    const ushort* __restrict__ A, const ushort* __restrict__ Bw,
    ushort* __restrict__ v_t,
    float* __restrict__ of, const float* __restrict__ bias)
{
  __shared__ ushort smA[128 * 32];
  __shared__ ushort smB[128 * 32];
  const int tid = threadIdx.x;
  const int l = tid & 63;
  const int w = tid >> 6;
  const int x = l & 15, g = l >> 4;
  const int wm = w >> 1, wn = w & 1;
  const int bm = blockIdx.x, bn = blockIdx.y;

  const ushort* gA[2]; const ushort* gB[2]; int ldso[2];
#pragma unroll
  for (int p = 0; p < 2; ++p) {
    int q = p * 256 + tid;
    gA[p] = &A[(size_t)(bm * 128 + (q >> 2)) * AST + (q & 3) * 8];
    gB[p] = &Bw[(size_t)(bn * 128 + (q >> 2)) * BROW + (q & 3) * 8];
    ldso[p] = (p * 256 + w * 64) * 8;
  }

  f32x4 acc[4][4] = {};

  for (int k0 = 0; k0 < KK; k0 += 32) {
    __syncthreads();
#pragma unroll
    for (int p = 0; p < 2; ++p) {
      gld16(gA[p] + k0, &smA[ldso[p]]);
      gld16(gB[p] + (k0 & (BROW - 1)), &smB[ldso[p]]);
    }
    __syncthreads();
    bf16x8 af[4], bf_[4];
#pragma unroll
    for (int m = 0; m < 4; ++m)
      af[m] = *(const bf16x8*)&smA[(wm * 64 + m * 16 + x) * 32 + g * 8];
#pragma unroll
    for (int n = 0; n < 4; ++n)
      bf_[n] = *(const bf16x8*)&smB[(wn * 64 + n * 16 + x) * 32 + g * 8];
#pragma unroll
    for (int m = 0; m < 4; ++m)
#pragma unroll
      for (int n = 0; n < 4; ++n)
        acc[m][n] = __builtin_amdgcn_mfma_f32_16x16x32_bf16(af[m], bf_[n], acc[m][n], 0, 0, 0);
  }

#pragma unroll
  for (int m = 0; m < 4; ++m)
#pragma unroll
    for (int n = 0; n < 4; ++n)
#pragma unroll
      for (int r = 0; r < 4; ++r) {
        int rowg = bm * 128 + wm * 64 + m * 16 + g * 4 + r;
        int colg = bn * 128 + wn * 64 + n * 16 + x;
        float v = acc[m][n][r];
        if (EPI == 2) {
          of[(size_t)rowg * D + colg] = v + bias[colg];
        } else {
          int bi = rowg >> 12, ntok = rowg & 4095;
          int cg = colg & 1023;
          int h = cg >> 6, hd = cg & 63;
          size_t bhb = (size_t)(bi * H + h) * (S * HD);
          // plain V^T (32x32 PV A-frag reads contiguous tokens; no k-slot permutation)
          v_t[bhb + (size_t)hd * S + ntok] = f2bf(v);
        }
      }
}

// ---------------- flash16: 32x32x16 MFMA port (half the MFMA issues), T12 permlane P-pack ----------------
// Wave covers 32 q-rows (q = l&31), lane holds 32 scores: tile T in{0,1}, reg r:
// k = 64kv + 32T + (r&3) + 8(r>>2) + 4(l>>5). P->B-frag via v_permlane32_swap (l <-> l+32).
__global__ __launch_bounds__(256) void flash16(
    const ushort* __restrict__ qhi, const ushort* __restrict__ qlo,
    const ushort* __restrict__ khi, const ushort* __restrict__ klo,
    const ushort* __restrict__ vt, ushort* __restrict__ ctx)
{
  __shared__ ushort smKhi[2][64 * 64];
  __shared__ ushort smKlo[2][64 * 64];
  __shared__ ushort smVT[2][64 * 64];

  const int tid = threadIdx.x;
  const int l = tid & 63;
  const int w = tid >> 6;
  const int q31 = l & 31;
  const int g2 = l >> 5;        // 0..1
  const int l7 = l & 7;
  const int bh = blockIdx.x;
  const int qt = (int)(gridDim.y - 1) - (int)blockIdx.y;   // heavy tiles first
  const int qbase = qt * 128;
  const size_t qkbase = (size_t)bh * S * HD;

  int soff_k[2]; size_t soff_v[2]; int ldso[2];
#pragma unroll
  for (int p = 0; p < 2; ++p) {
    int q = p * 256 + tid;
    int r2 = q >> 3;
    int sb = (q & 7) ^ (r2 & 7);
    soff_k[p] = r2 * HD + sb * 8;
    soff_v[p] = (size_t)r2 * S + sb * 8;
    ldso[p] = (p * 256 + w * 64) * 8;
  }
  const ushort* khb = khi + qkbase;
  const ushort* klb = klo + qkbase;
  const ushort* vtb = vt + qkbase;

  // Q fragments (B-operand of 32x32x16): [hi/lo][step]; lane: q=q31, d = 16*step + 8*g2 + j
  bf16x8 bq[2][4];
  {
    int qrow = qbase + w * 32 + q31;
    size_t base = qkbase + (size_t)qrow * HD + g2 * 8;
#pragma unroll
    for (int s2 = 0; s2 < 4; ++s2) {
      bq[0][s2] = *(const bf16x8*)&qhi[base + s2 * 16];
      bq[1][s2] = *(const bf16x8*)&qlo[base + s2 * 16];
    }
  }

  float mrun = -1e30f;
  float lrun = 0.f;            // lane-partial (k-half); reduced at epilogue
  f32x16 oacc0 = {}, oacc1 = {};

  const int kvmax = (qbase + 127) >> 6;
  const int qmaxw = qbase + w * 32 + 31;
  const float C1 = 0.125f * 1.44269504f;
  const float TH = 8.0f / C1;

#pragma unroll
  for (int p = 0; p < 2; ++p) {
    gld16(khb + soff_k[p], &smKhi[0][ldso[p]]);
    gld16(klb + soff_k[p], &smKlo[0][ldso[p]]);
    gld16(vtb + soff_v[p], &smVT[0][ldso[p]]);
  }
  __syncthreads();

  int cur = 0;
  for (int kv = 0; kv <= kvmax; ++kv) {
    if (kv < kvmax) {
      const ushort* kh = khb + (size_t)(kv + 1) * (64 * HD);
      const ushort* kl = klb + (size_t)(kv + 1) * (64 * HD);
      const ushort* vp = vtb + (size_t)(kv + 1) * 64;
      int nb = cur ^ 1;
#pragma unroll
      for (int p = 0; p < 2; ++p) {
        gld16(kh + soff_k[p], &smKhi[nb][ldso[p]]);
        gld16(kl + soff_k[p], &smKlo[nb][ldso[p]]);
        gld16(vp + soff_v[p], &smVT[nb][ldso[p]]);
      }
    }

    if (kv * 64 <= qmaxw) {
      const ushort* bKhi = smKhi[cur];
      const ushort* bKlo = smKlo[cur];
      const ushort* bVT = smVT[cur];

      // ---- QK^T swapped, 32x32x16: sc[T] covers k-tokens [32T, 32T+32) x 32 q ----
      f32x16 sc0 = {}, sc1 = {};
      __builtin_amdgcn_s_setprio(1);
#pragma unroll
      for (int s2 = 0; s2 < 4; ++s2) {
        {
          int row = q31;                       // tile 0: tokens 0..31
          int pb = row * 64 + (((2 * s2 + g2)) ^ l7) * 8;
          bf16x8 kH = *(const bf16x8*)&bKhi[pb];
          bf16x8 kL = *(const bf16x8*)&bKlo[pb];
          sc0 = __builtin_amdgcn_mfma_f32_32x32x16_bf16(kH, bq[0][s2], sc0, 0, 0, 0);
          sc0 = __builtin_amdgcn_mfma_f32_32x32x16_bf16(kL, bq[0][s2], sc0, 0, 0, 0);
          sc0 = __builtin_amdgcn_mfma_f32_32x32x16_bf16(kH, bq[1][s2], sc0, 0, 0, 0);
        }
        {
          int row = 32 + q31;                  // tile 1: tokens 32..63
          int pb = row * 64 + (((2 * s2 + g2)) ^ l7) * 8;
          bf16x8 kH = *(const bf16x8*)&bKhi[pb];
          bf16x8 kL = *(const bf16x8*)&bKlo[pb];
          sc1 = __builtin_amdgcn_mfma_f32_32x32x16_bf16(kH, bq[0][s2], sc1, 0, 0, 0);
          sc1 = __builtin_amdgcn_mfma_f32_32x32x16_bf16(kL, bq[0][s2], sc1, 0, 0, 0);
          sc1 = __builtin_amdgcn_mfma_f32_32x32x16_bf16(kH, bq[1][s2], sc1, 0, 0, 0);
        }
      }
      __builtin_amdgcn_s_setprio(0);

      // ---- mask (diagonal tiles only) ----
      if (kv * 64 + 63 > qbase + w * 32) {
        int qglob = qbase + w * 32 + q31;
        int kb = kv * 64 + 4 * g2;
#pragma unroll
        for (int r = 0; r < 16; ++r) {
          int k5 = (r & 3) + 8 * (r >> 2);
          if (kb + k5 > qglob) sc0[r] = -1e30f;
          if (kb + 32 + k5 > qglob) sc1[r] = -1e30f;
        }
      }

      // ---- softmax (lane-local 32 + 1 swap-pair shfl in rare trip) ----
      float mt[8];
#pragma unroll
      for (int r = 0; r < 8; ++r)
        mt[r] = fmaxf(fmaxf(sc0[2 * r], sc0[2 * r + 1]), fmaxf(sc1[2 * r], sc1[2 * r + 1]));
      float mloc = fmaxf(fmaxf(fmaxf(mt[0], mt[1]), fmaxf(mt[2], mt[3])),
                         fmaxf(fmaxf(mt[4], mt[5]), fmaxf(mt[6], mt[7])));
      if (__any(mloc > mrun + TH)) {
        float mx = fmaxf(mloc, __shfl_xor(mloc, 32));
        float mnew = fmaxf(mrun, mx);
        float scal = vexp2((mrun - mnew) * C1);
        mrun = mnew;
        lrun *= scal;
        oacc0 *= scal;
        oacc1 *= scal;
      }
      float mc = mrun * C1;
#pragma unroll
      for (int r = 0; r < 16; ++r) {
        sc0[r] = vexp2(sc0[r] * C1 - mc);
        sc1[r] = vexp2(sc1[r] * C1 - mc);
      }
      float st[8];
#pragma unroll
      for (int r = 0; r < 8; ++r)
        st[r] = (sc0[2 * r] + sc0[2 * r + 1]) + (sc1[2 * r] + sc1[2 * r + 1]);
      lrun += ((st[0] + st[1]) + (st[2] + st[3])) + ((st[4] + st[5]) + (st[6] + st[7]));

      // ---- P pack -> B-frags via permlane32_swap (T12): per k-slice s2: words j01,j23,j45,j67 ----
      uint32_t pbw[4][4];
#pragma unroll
      for (int s2 = 0; s2 < 4; ++s2) {
        const int s1 = s2 & 1;
#pragma unroll
        for (int p = 0; p < 2; ++p) {
          // r = 2p + 4c + 8*s1 within tile T = s2>>1; value j = (r&3) + 4*g2
          uint32_t a, b;
          if (s2 < 2) {
            a = cvtpk(sc0[2 * p + 8 * s1], sc0[2 * p + 1 + 8 * s1]);          // c=0
            b = cvtpk(sc0[2 * p + 4 + 8 * s1], sc0[2 * p + 5 + 8 * s1]);      // c=1
          } else {
            a = cvtpk(sc1[2 * p + 8 * s1], sc1[2 * p + 1 + 8 * s1]);
            b = cvtpk(sc1[2 * p + 4 + 8 * s1], sc1[2 * p + 5 + 8 * s1]);
          }
          asm volatile("v_permlane32_swap_b32 %0, %1" : "+v"(a), "+v"(b));
          pbw[s2][p] = a;        // j = 2p, 2p+1   (low half, c = own g2)
          pbw[s2][2 + p] = b;    // j = 2p+4, 2p+5 (high half, c = own g2)
        }
      }

      // ---- PV: O^T[d][q] += V^T * P, 32x32x16; A = V^T rows d, 8 contiguous tokens ----
      __builtin_amdgcn_s_setprio(1);
#pragma unroll
      for (int s2 = 0; s2 < 4; ++s2) {
        bf16x8 bp = pack4(pbw[s2][0], pbw[s2][1], pbw[s2][2], pbw[s2][3]);
        {
          bf16x8 vf = *(const bf16x8*)&bVT[(q31)*64 + (((2 * s2 + g2)) ^ l7) * 8];
          oacc0 = __builtin_amdgcn_mfma_f32_32x32x16_bf16(vf, bp, oacc0, 0, 0, 0);
        }
        {
          bf16x8 vf = *(const bf16x8*)&bVT[(32 + q31) * 64 + (((2 * s2 + g2)) ^ l7) * 8];
          oacc1 = __builtin_amdgcn_mfma_f32_32x32x16_bf16(vf, bp, oacc1, 0, 0, 0);
        }
      }
      __builtin_amdgcn_s_setprio(0);
    }

    __syncthreads();
    cur ^= 1;
  }

  const int b = bh >> 4, h = bh & 15;
  {
    float ls = lrun + __shfl_xor(lrun, 32);
    float inv = 1.0f / ls;
    int tok = qbase + w * 32 + q31;
    size_t rbase = (size_t)(b * S + tok) * D + h * 64;
#pragma unroll
    for (int r2 = 0; r2 < 4; ++r2) {
      uint2 uu;
      uu.x = cvtpk(oacc0[4 * r2] * inv, oacc0[4 * r2 + 1] * inv);
      uu.y = cvtpk(oacc0[4 * r2 + 2] * inv, oacc0[4 * r2 + 3] * inv);
      *(uint2*)&ctx[rbase + 8 * r2 + 4 * g2] = uu;
      uu.x = cvtpk(oacc1[4 * r2] * inv, oacc1[4 * r2 + 1] * inv);
      uu.y = cvtpk(oacc1[4 * r2 + 2] * inv, oacc1[4 * r2 + 3] * inv);
      *(uint2*)&ctx[rbase + 32 + 8 * r2 + 4 * g2] = uu;
    }
  }
}

extern "C" void kernel_launch(void* const* d_in, const int* in_sizes, int n_in,
                              void* d_out, int out_size, void* d_ws, size_t ws_size,
                              hipStream_t stream) {
  const float* x  = (const float*)d_in[0];
  const float* Wq = (const float*)d_in[1];
  const float* Wk = (const float*)d_in[2];
  const float* Wv = (const float*)d_in[3];
  const float* Wo = (const float*)d_in[4];
  const float* bo = (const float*)d_in[5];
  float* out = (float*)d_out;

  if (ws_size < (size_t)120 * 1024 * 1024) return;

  char* ws = (char*)d_ws;
  const size_t MB = 1024 * 1024;
  ushort* xcat = (ushort*)(ws);              // 32MB; ctx aliases (xcat dead after projections)
  ushort* ctx  = (ushort*)(ws);
  ushort* wcat = (ushort*)(ws + 32 * MB);    // 6MB [3072][1024]
  ushort* wob  = (ushort*)(ws + 38 * MB);    // 2MB
  ushort* qhi  = (ushort*)(ws + 40 * MB);    // 16MB each
  ushort* qlo  = (ushort*)(ws + 56 * MB);
  ushort* khi  = (ushort*)(ws + 72 * MB);
  ushort* klo  = (ushort*)(ws + 88 * MB);
  ushort* vt   = (ushort*)(ws + 104 * MB);

  prep_x<<<2048, 256, 0, stream>>>(x, xcat);
  prep_w<<<1024, 256, 0, stream>>>(Wq, Wk, Wv, Wo, wcat, wob);

  gemm256<<<dim3(32, 8), 512, 0, stream>>>(xcat, wcat, qhi, qlo, khi, klo);
  gemm97<1, 1024, 1024, 2048><<<dim3(64, 8), 256, 0, stream>>>(
      xcat, wcat + 2 * D * D, vt, nullptr, nullptr);

  flash16<<<dim3(BATCH * H, S / 128), 256, 0, stream>>>(qhi, qlo, khi, klo, vt, ctx);

  gemm97<2, 1024, 1024, 1024><<<dim3(64, 8), 256, 0, stream>>>(
      ctx, wob, nullptr, out, bo);
}